// Round 1
// 1497.612 us; speedup vs baseline: 1.5540x; 1.5540x over previous
//
#include <hip/hip_runtime.h>
#include <hip/hip_bf16.h>
#include <stdint.h>

// Problem constants
#define NN   16384   // nodes
#define FI   128     // in feats
#define FH   128     // hidden
#define FO   64      // out feats

// Kernel-2 tiling
#define BM   32      // rows of adj per block
#define BK   64      // K-columns per tile
#define LDK  72      // padded bf16 leading dim (+8 bf16 -> conflict-free b128 frags)
#define NT   (NN / BK)  // 256 K-iterations

typedef float f32x4 __attribute__((ext_vector_type(4)));
typedef short s16x8 __attribute__((ext_vector_type(8)));
typedef short s16x4 __attribute__((ext_vector_type(4)));

__device__ __forceinline__ unsigned short f2bf(float f) {
    union { float f; unsigned u; } v; v.f = f;
    unsigned u = v.u;
    return (unsigned short)((u + 0x7FFFu + ((u >> 16) & 1u)) >> 16);  // RNE
}

// ---------------------------------------------------------------------------
// Kernel 1: S1T[n][k] = sum_f x[k][f] * W1[f][n], stored bf16 TRANSPOSED
// (n-major) so kernel 2 can stage B-fragments with contiguous b128 reads.
// ---------------------------------------------------------------------------
__global__ __launch_bounds__(256) void k1_s1t(const float* __restrict__ x,
                                              const float* __restrict__ W1,
                                              unsigned short* __restrict__ S1T) {
    __shared__ float w1s[FI][FH];     // [f][n], 64 KB, reads are wave-uniform (broadcast)
    __shared__ float xs[64][132];     // 64 k-rows, pad 132 -> uniform 8-way b128 (optimal)

    const int t  = threadIdx.x;
    const int b  = blockIdx.x;        // 256 blocks
    const int k0 = b * 64;

    float* wflat = &w1s[0][0];
    for (int i = t; i < FI * FH; i += 256) wflat[i] = W1[i];

    #pragma unroll
    for (int s = 0; s < 8; ++s) {
        int idx = t + 256 * s;              // 2048 float4 chunks
        int r   = idx >> 5;                 // 0..63
        int f4  = idx & 31;
        f32x4 vv = *(const f32x4*)(x + (size_t)(k0 + r) * FI + f4 * 4);
        *(f32x4*)(&xs[r][f4 * 4]) = vv;
    }
    __syncthreads();

    const int w = t >> 6;                   // wave = n-group (32 cols)
    const int l = t & 63;                   // lane = k-row

    float acc[32];
    #pragma unroll
    for (int j = 0; j < 32; ++j) acc[j] = 0.f;

    for (int f4 = 0; f4 < 32; ++f4) {
        f32x4 xv = *(const f32x4*)(&xs[l][f4 * 4]);
        #pragma unroll
        for (int e = 0; e < 4; ++e) {
            const int f = f4 * 4 + e;
            #pragma unroll
            for (int cth = 0; cth < 8; ++cth) {
                f32x4 wv = *(const f32x4*)(&w1s[f][w * 32 + cth * 4]);  // broadcast
                acc[cth * 4 + 0] += xv[e] * wv[0];
                acc[cth * 4 + 1] += xv[e] * wv[1];
                acc[cth * 4 + 2] += xv[e] * wv[2];
                acc[cth * 4 + 3] += xv[e] * wv[3];
            }
        }
    }

    const int k = k0 + l;
    #pragma unroll
    for (int j = 0; j < 32; ++j) {
        const int n = w * 32 + j;
        S1T[(size_t)n * NN + k] = f2bf(acc[j]);   // lanes -> consecutive k, coalesced
    }
}

// ---------------------------------------------------------------------------
// Kernel 2: T = adj @ S1  (fp32 adj streamed from HBM, converted to bf16
// in-register, MFMA 16x16x32 bf16).  Column-sum partials now go to a
// BLOCK-PRIVATE slab cpart[block][k] via one coalesced 256 B store per iter —
// NO atomics in the hot loop (the old 33.5M contended atomicAdds caused
// ~525 MB of RMW write traffic and serialized every barrier).
// 2-tile-deep register prefetch hides HBM latency across the vmcnt drain.
// ---------------------------------------------------------------------------
__global__ __launch_bounds__(256, 2) void k2_agg(const float* __restrict__ adj,
                                                 const unsigned short* __restrict__ S1T,
                                                 float* __restrict__ T,
                                                 float* __restrict__ cpart) {
    __shared__ unsigned short aA[2][BM][LDK];   //  9,216 B
    __shared__ unsigned short bB[2][FH][LDK];   // 36,864 B
    __shared__ float cs[2][4][BK];              //  2,048 B  (total ~47 KB -> 2 blocks/CU)

    const int  t    = threadIdx.x;
    const long m0   = (long)blockIdx.x * BM;
    const int  w    = t >> 6;
    const int  l    = t & 63;
    const int  ar   = t >> 4;       // adj stage row 0..15 (and +16)
    const int  ac4  = t & 15;       // adj stage float4-col
    const int  sn   = t >> 3;       // s1 stage row 0..31 (and +32k)
    const int  sch  = t & 7;        // s1 stage 16B chunk
    const int  m    = l & 15;
    const int  quad = l >> 4;

    f32x4 acc[2][2];
    #pragma unroll
    for (int i = 0; i < 2; ++i)
        #pragma unroll
        for (int j = 0; j < 2; ++j) acc[i][j] = (f32x4){0.f, 0.f, 0.f, 0.f};

    // two register prefetch sets (named, NOT runtime-indexed -> stay in VGPRs)
    f32x4 paA0, paA1, paB0, paB1;
    s16x8 psA[4], psB[4];

#define LOAD_TILE(PA0, PA1, PS, KT) do {                                          \
    const long koff_ = (long)(KT) * BK;                                           \
    PA0 = *(const f32x4*)(adj + (m0 + ar) * NN + koff_ + ac4 * 4);                \
    PA1 = *(const f32x4*)(adj + (m0 + ar + 16) * NN + koff_ + ac4 * 4);           \
    _Pragma("unroll")                                                             \
    for (int s_ = 0; s_ < 4; ++s_)                                                \
        PS[s_] = *(const s16x8*)(S1T + (size_t)(sn + 32 * s_) * NN + koff_ + sch * 8); \
} while (0)

#define STAGE(SB, PA0, PA1, PS) do {                                              \
    s16x4 q0_, q1_;                                                               \
    _Pragma("unroll")                                                             \
    for (int j_ = 0; j_ < 4; ++j_) {                                              \
        q0_[j_] = (short)f2bf(PA0[j_]);                                           \
        q1_[j_] = (short)f2bf(PA1[j_]);                                           \
    }                                                                             \
    *(s16x4*)(&aA[SB][ar][ac4 * 4])      = q0_;                                   \
    *(s16x4*)(&aA[SB][ar + 16][ac4 * 4]) = q1_;                                   \
    _Pragma("unroll")                                                             \
    for (int s_ = 0; s_ < 4; ++s_)                                                \
        *(s16x8*)(&bB[SB][sn + 32 * s_][sch * 8]) = PS[s_];                       \
    /* per-wave colsum partial over this wave's 8 rows -> cs[SB][w][0..63] */     \
    _Pragma("unroll")                                                             \
    for (int j_ = 0; j_ < 4; ++j_) {                                              \
        float pv_ = PA0[j_] + PA1[j_];                                            \
        pv_ += __shfl_xor(pv_, 16);                                               \
        pv_ += __shfl_xor(pv_, 32);                                               \
        if (l < 16) cs[SB][w][l * 4 + j_] = pv_;                                  \
    }                                                                             \
} while (0)

#define COMPUTE(SB) do {                                                          \
    _Pragma("unroll")                                                             \
    for (int ks = 0; ks < 2; ++ks) {                                              \
        s16x8 af_[2], bf_[2];                                                     \
        _Pragma("unroll")                                                         \
        for (int mt = 0; mt < 2; ++mt)                                            \
            af_[mt] = *(const s16x8*)(&aA[SB][mt * 16 + m][ks * 32 + quad * 8]);  \
        _Pragma("unroll")                                                         \
        for (int nt = 0; nt < 2; ++nt)                                            \
            bf_[nt] = *(const s16x8*)(&bB[SB][w * 32 + nt * 16 + m][ks * 32 + quad * 8]); \
        _Pragma("unroll")                                                         \
        for (int mt = 0; mt < 2; ++mt)                                            \
            _Pragma("unroll")                                                     \
            for (int nt = 0; nt < 2; ++nt)                                        \
                acc[mt][nt] = __builtin_amdgcn_mfma_f32_16x16x32_bf16(            \
                    af_[mt], bf_[nt], acc[mt][nt], 0, 0, 0);                      \
    }                                                                             \
} while (0)

    // cross-wave reduce (4 partials) + one coalesced 256 B store, wave 0 only
#define FLUSH(SB, KT) do {                                                        \
    if (t < BK)                                                                   \
        cpart[(size_t)blockIdx.x * NN + (size_t)(KT) * BK + t] =                  \
            cs[SB][0][t] + cs[SB][1][t] + cs[SB][2][t] + cs[SB][3][t];            \
} while (0)

    LOAD_TILE(paA0, paA1, psA, 0);
    LOAD_TILE(paB0, paB1, psB, 1);
    STAGE(0, paA0, paA1, psA);
    __syncthreads();

    for (int kt2 = 0; kt2 < NT; kt2 += 2) {
        // ---- even sub-iter: compute tile kt2 from buf 0 ----
        if (kt2 + 2 < NT) LOAD_TILE(paA0, paA1, psA, kt2 + 2);  // prefetch depth 2
        FLUSH(0, kt2);
        COMPUTE(0);
        STAGE(1, paB0, paB1, psB);                              // tile kt2+1 -> buf 1
        __syncthreads();

        // ---- odd sub-iter: compute tile kt2+1 from buf 1 ----
        if (kt2 + 3 < NT) LOAD_TILE(paB0, paB1, psB, kt2 + 3);
        FLUSH(1, kt2 + 1);
        COMPUTE(1);
        if (kt2 + 2 < NT) STAGE(0, paA0, paA1, psA);            // tile kt2+2 -> buf 0
        __syncthreads();
    }

#undef LOAD_TILE
#undef STAGE
#undef COMPUTE
#undef FLUSH

    // epilogue: C/D layout col=lane&15, row=quad*4+reg
    #pragma unroll
    for (int mt = 0; mt < 2; ++mt)
        #pragma unroll
        for (int nt = 0; nt < 2; ++nt) {
            const int col = w * 32 + nt * 16 + m;
            #pragma unroll
            for (int r = 0; r < 4; ++r) {
                const long row = m0 + mt * 16 + quad * 4 + r;
                T[row * FH + col] = acc[mt][nt][r];
            }
        }
}

// ---------------------------------------------------------------------------
// Kernel 3: finish colsum c[k] = sum_b cpart[b][k] (coalesced, block-local),
// then v[m] = sum_k c[k] * relu(T[k][m] + b1[m])
// ---------------------------------------------------------------------------
__global__ __launch_bounds__(256) void k3_v(const float* __restrict__ T,
                                            const float* __restrict__ cpart,
                                            const float* __restrict__ b1,
                                            float* __restrict__ v) {
    __shared__ float vp[FH];
    __shared__ float cw[4][64];
    __shared__ float cloc[64];

    const int t = threadIdx.x;
    const int b = blockIdx.x;      // 256 blocks x 64 rows
    const int w = t >> 6;
    const int l = t & 63;

    // 512-way partial reduction for this block's 64 k-rows.
    // wave w sums blocks {w, w+4, w+8, ...}; lanes -> consecutive k (coalesced).
    float s = 0.f;
    #pragma unroll 8
    for (int i = 0; i < 128; ++i)
        s += cpart[(size_t)(w + 4 * i) * NN + b * 64 + l];
    cw[w][l] = s;
    if (t < FH) vp[t] = 0.f;
    __syncthreads();
    if (t < 64) cloc[t] = cw[0][t] + cw[1][t] + cw[2][t] + cw[3][t];
    __syncthreads();

    const int kk = t >> 2;
    const int mq = t & 3;
    const int k  = b * 64 + kk;
    const float ck = cloc[kk];

    #pragma unroll
    for (int j4 = 0; j4 < 8; ++j4) {
        f32x4 tv = *(const f32x4*)(T + (size_t)k * FH + mq * 32 + j4 * 4);
        f32x4 bv = *(const f32x4*)(b1 + mq * 32 + j4 * 4);
        #pragma unroll
        for (int e = 0; e < 4; ++e) {
            float h = tv[e] + bv[e];
            h = h > 0.f ? h : 0.f;
            atomicAdd(&vp[mq * 32 + j4 * 4 + e], ck * h);
        }
    }
    __syncthreads();
    if (t < FH) atomicAdd(&v[t], vp[t]);
}

// ---------------------------------------------------------------------------
// Kernel 4: pooled = v @ W2 + N*b2 ; out = pooled @ W_out + b_out
// ---------------------------------------------------------------------------
__global__ void k4_out(const float* __restrict__ v, const float* __restrict__ W2,
                       const float* __restrict__ b2, const float* __restrict__ Wout,
                       const float* __restrict__ bout, float* __restrict__ out) {
    const int j = threadIdx.x;  // 64
    float pj = (float)NN * b2[j];
    for (int mm = 0; mm < FH; ++mm) pj += v[mm] * W2[mm * FO + j];
    float s = pj * Wout[j];
    #pragma unroll
    for (int off = 32; off; off >>= 1) s += __shfl_down(s, off);
    if (j == 0) out[0] = s + bout[0];
}

// ---------------------------------------------------------------------------
extern "C" void kernel_launch(void* const* d_in, const int* in_sizes, int n_in,
                              void* d_out, int out_size, void* d_ws, size_t ws_size,
                              hipStream_t stream) {
    const float* x    = (const float*)d_in[0];
    const float* adj  = (const float*)d_in[1];
    const float* W1   = (const float*)d_in[2];
    const float* b1   = (const float*)d_in[3];
    const float* W2   = (const float*)d_in[4];
    const float* b2   = (const float*)d_in[5];
    const float* Wout = (const float*)d_in[6];
    const float* bout = (const float*)d_in[7];
    float* out = (float*)d_out;

    char* ws = (char*)d_ws;
    unsigned short* S1T = (unsigned short*)ws;                 // 4 MiB bf16 [128][16384]
    float* T     = (float*)(ws + (4u  << 20));                 // 8 MiB fp32 [16384][128]
    float* cpart = (float*)(ws + (12u << 20));                 // 32 MiB fp32 [512][16384]
    float* v     = (float*)(ws + (44u << 20));                 // 512 B fp32 [128]

    hipMemsetAsync(v, 0, 512, stream);                         // zero v only

    k1_s1t<<<256, 256, 0, stream>>>(x, W1, S1T);
    k2_agg<<<512, 256, 0, stream>>>(adj, S1T, T, cpart);
    k3_v  <<<256, 256, 0, stream>>>(T, cpart, b1, v);
    k4_out<<<1, 64, 0, stream>>>(v, W2, b2, Wout, bout, out);
}